// Round 7
// baseline (588.940 us; speedup 1.0000x reference)
//
#include <hip/hip_runtime.h>
#include <hip/hip_bf16.h>
#include <cstdio>

// ---------------------------------------------------------------------------
// Attn_59940563583594: hidden[32,1024,768] -> QKV -> causal attn (no 1/sqrt(d))
//                      -> relu MLP(768->64) -> out[32,1024,2] fp32
// Numerics (verified R2-R8: absmax 9.8e-4 vs 3.8e-3 threshold):
//   f16 storage/MFMA for hidden/W/q/k, no-max softmax (exp clamp 80,
//   unnormalized bf16 p, fp32 row sums, normalize in PV), bf16 PV + MLP.
// R16: accounting showed logits+pv ~250 us vs ~55 us floor, invariant
//   across 3 staging structures -> the LDS staging itself is the overhead:
//   their operands are cache-resident (q16/k16 in L3; pu/vT in the SAME
//   XCD's L2 via b<->xcd affinity) and MFMA fragments are 16B-contiguous
//   per lane in global memory. Common-mistake #7: drop LDS staging when
//   data cache-fits. logits/pv rewritten as LDS-free direct-load kernels
//   (no barriers in K-loop, frags global->VGPR, same tiles/epilogues,
//   bitwise-identical accumulation). cvt_all -> grid-stride 2048 blocks,
//   f32x8 -> f16x8 (16B stores). qkv kept at R13 best (171 us); mlp R15.
// ---------------------------------------------------------------------------

typedef _Float16 f16;
typedef f16    f16x8 __attribute__((ext_vector_type(8)));
typedef f16    f16x4 __attribute__((ext_vector_type(4)));
typedef __bf16 bfx8  __attribute__((ext_vector_type(8)));
typedef __bf16 bfx4  __attribute__((ext_vector_type(4)));
typedef float  f32x4 __attribute__((ext_vector_type(4)));

#define MFMA_F16(a,b,c)  __builtin_amdgcn_mfma_f32_16x16x32_f16((a),(b),(c),0,0,0)
#define MFMA_BF16(a,b,c) __builtin_amdgcn_mfma_f32_16x16x32_bf16((a),(b),(c),0,0,0)

static constexpr int LDT2 = 264;  // qkv v-transpose stride (128e x 256s)

__device__ __forceinline__ void gl_lds16(const void* g, void* l) {
    __builtin_amdgcn_global_load_lds(
        (const __attribute__((address_space(1))) void*)g,
        (__attribute__((address_space(3))) void*)l, 16, 0, 0);
}

// clobber-free waits, pinned with sched_barrier(0) (rule #18 / m201 pattern)
#define WAIT_VMCNT(n)                                        \
    do { asm volatile("s_waitcnt vmcnt(" #n ")");            \
         __builtin_amdgcn_sched_barrier(0); } while (0)
#define WAIT_LGKM0()                                         \
    do { asm volatile("s_waitcnt lgkmcnt(0)");               \
         __builtin_amdgcn_sched_barrier(0); } while (0)

// ---------------- fp32 -> f16/bf16 convert, grid-stride (R16) ---------------
__global__ __launch_bounds__(256) void cvt_all(
    const float* __restrict__ hidden,
    const float* __restrict__ Wq, const float* __restrict__ Wk, const float* __restrict__ Wv,
    const float* __restrict__ W1,
    f16* __restrict__ h16, f16* __restrict__ oq, f16* __restrict__ ok, f16* __restrict__ ov,
    __bf16* __restrict__ w1b)
{
    const int HID_C = 25165824 / 8;            // hidden chunks of 8 f32
    const int W_C   = 589824 / 8;              // per-weight chunks
    const int W1_C  = 49152 / 8;
    const int TOT   = HID_C + 3 * W_C + W1_C;  // 3,373,056
    for (int c = blockIdx.x * 256 + threadIdx.x; c < TOT; c += 2048 * 256) {
        const float* src;
        f16* dst = nullptr;
        __bf16* dstb = nullptr;
        int off;
        if (c < HID_C)                { src = hidden; dst = h16; off = c * 8; }
        else if (c < HID_C + W_C)     { src = Wq; dst = oq; off = (c - HID_C) * 8; }
        else if (c < HID_C + 2 * W_C) { src = Wk; dst = ok; off = (c - HID_C - W_C) * 8; }
        else if (c < HID_C + 3 * W_C) { src = Wv; dst = ov; off = (c - HID_C - 2 * W_C) * 8; }
        else                          { src = W1; dstb = w1b; off = (c - HID_C - 3 * W_C) * 8; }
        f32x4 a = *(const f32x4*)(src + off);
        f32x4 b = *(const f32x4*)(src + off + 4);
        if (dstb) {
            bfx8 o;
            #pragma unroll
            for (int e = 0; e < 4; ++e) { o[e] = (__bf16)a[e]; o[e + 4] = (__bf16)b[e]; }
            *(bfx8*)(dstb + off) = o;
        } else {
            f16x8 o;
            #pragma unroll
            for (int e = 0; e < 4; ++e) { o[e] = (f16)a[e]; o[e + 4] = (f16)b[e]; }
            *(f16x8*)(dst + off) = o;
        }
    }
}

// ---- 8-phase QPHASE (qkv only): {ds_read A | stage | gate | barrier | lgkm0
//                                  | 16 MFMA | barrier}
#define QPHASE(fr0, STAGE_STMT, GATE_STMT)                                        \
    {                                                                             \
        f16x8 afr[2][2];                                                          \
        _Pragma("unroll")                                                         \
        for (int i = 0; i < 2; ++i) {                                             \
            _Pragma("unroll")                                                     \
            for (int kk = 0; kk < 2; ++kk)                                        \
                afr[i][kk] = *(const f16x8*)&SA[kk * 8192 + (wr8 + (fr0) + i) * 512 + lq]; \
        }                                                                         \
        STAGE_STMT;                                                               \
        GATE_STMT;                                                                \
        __builtin_amdgcn_s_barrier();                                             \
        WAIT_LGKM0();                                                             \
        __builtin_amdgcn_s_setprio(1);                                            \
        _Pragma("unroll")                                                         \
        for (int i = 0; i < 2; ++i) {                                             \
            _Pragma("unroll")                                                     \
            for (int jj = 0; jj < 4; ++jj) {                                      \
                acc[(fr0) + i][jj] = MFMA_F16(afr[i][0], bfr[jj][0], acc[(fr0) + i][jj]); \
                acc[(fr0) + i][jj] = MFMA_F16(afr[i][1], bfr[jj][1], acc[(fr0) + i][jj]); \
            }                                                                     \
        }                                                                         \
        __builtin_amdgcn_s_setprio(0);                                            \
        __builtin_amdgcn_s_barrier();                                             \
    }

// ---------------- K1: fused q,k,v projections, 256x256 8-phase (R13) --------
// grid 1152 = 8 xcd * (3 nt * 3 z * 16 mi); mt = xcd + 8*mi; 512 threads.
__global__ __launch_bounds__(512, 2) void qkv_kernel(
    const f16* __restrict__ h16,
    const f16* __restrict__ wq, const f16* __restrict__ wk, const f16* __restrict__ wv,
    const float* __restrict__ bq, const float* __restrict__ bk, const float* __restrict__ bv,
    f16* __restrict__ q16, f16* __restrict__ k16, __bf16* __restrict__ vT)
{
    const int f = blockIdx.x;
    const int xcd = f & 7;
    const int j = f >> 3;
    const int nt = j % 3;
    const int z  = (j / 3) % 3;
    const int mi = j / 9;                 // [0,16)
    const int mt = xcd + 8 * mi;          // [0,128)
    const int m0 = mt * 256, n0 = nt * 256;

    const f16* W = (z == 0) ? wq : (z == 1) ? wk : wv;
    const float* bias = (z == 0) ? bq : (z == 1) ? bk : bv;

    __shared__ alignas(16) f16 S[65536];  // 128 KB

    const int t = threadIdx.x, lane = t & 63, wave = t >> 6;
    const int wr = wave >> 2, wc = wave & 3;      // 2M x 4N wave grid
    const int wr8 = wr * 8;
    const int quad = lane >> 4, l16 = lane & 15;
    const int lq = quad * 128 + l16 * 8;

    const f16* gA = h16 + (size_t)(m0 + l16) * 768 + quad * 8;
    const f16* gB = W   + (size_t)(n0 + l16) * 768 + quad * 8;
    int gofs[2], lofs[2];
    #pragma unroll
    for (int u = 0; u < 2; ++u) {
        int unit = wave * 2 + u;
        int kk = unit >> 3, c = unit & 7;
        gofs[u] = c * 16 * 768 + kk * 32;
        lofs[u] = kk * 8192 + c * 512;
    }
    auto stage = [&](int kt, int mat, int half) {
        const f16* gp = (mat ? gB : gA) + half * (128 * 768) + kt * 64;
        f16* lp = &S[(kt & 1) * 32768 + mat * 16384 + half * 4096];
        gl_lds16(gp + gofs[0], lp + lofs[0]);
        gl_lds16(gp + gofs[1], lp + lofs[1]);
    };

    f32x4 acc[8][4] = {};

    stage(0, 0, 0); stage(0, 0, 1); stage(0, 1, 0); stage(0, 1, 1);
    stage(1, 1, 0); stage(1, 1, 1);
    WAIT_VMCNT(4);   // kt0 landed
    __builtin_amdgcn_s_barrier();

    f16x8 bfr[4][2];
    for (int kt = 0; kt < 12; ++kt) {
        const f16* SA = &S[(kt & 1) * 32768];
        const f16* SB = SA + 16384;
        #pragma unroll
        for (int jj = 0; jj < 4; ++jj) {
            #pragma unroll
            for (int kk = 0; kk < 2; ++kk)
                bfr[jj][kk] = *(const f16x8*)&SB[kk * 8192 + (wc * 4 + jj) * 512 + lq];
        }
        QPHASE(0, { if (kt + 1 < 12) stage(kt + 1, 0, 0); }, {});
        QPHASE(2, { if (kt + 1 < 12) stage(kt + 1, 0, 1); }, {});
        QPHASE(4, { if (kt + 2 < 12) stage(kt + 2, 1, 0); }, {});
        QPHASE(6, { if (kt + 2 < 12) stage(kt + 2, 1, 1); },
               {
                   if (kt + 2 < 12)       WAIT_VMCNT(4);
                   else if (kt + 1 < 12)  WAIT_VMCNT(0);
               });
    }

    if (z < 2) {
        f16* out = z ? k16 : q16;
        #pragma unroll
        for (int jj = 0; jj < 4; ++jj) {
            int col = n0 + wc * 64 + jj * 16 + l16;
            float bb = bias[col];
            #pragma unroll
            for (int fi = 0; fi < 8; ++fi) {
                #pragma unroll
                for (int r = 0; r < 4; ++r) {
                    int row = m0 + wr * 128 + fi * 16 + quad * 4 + r;
                    out[(size_t)row * 768 + col] = (f16)(acc[fi][jj][r] + bb);
                }
            }
        }
    } else {
        __bf16* Tb = (__bf16*)S;
        const int halfw = wc >> 1;
        const int bofs = (m0 >> 10) * 768;
        const int s0 = m0 & 1023;
        #pragma unroll
        for (int half = 0; half < 2; ++half) {
            __syncthreads();
            if (halfw == half) {
                #pragma unroll
                for (int jj = 0; jj < 4; ++jj) {
                    int el = (wc & 1) * 64 + jj * 16 + l16;
                    float bb = bias[n0 + half * 128 + el];
                    #pragma unroll
                    for (int fi = 0; fi < 8; ++fi) {
                        #pragma unroll
                        for (int r = 0; r < 4; ++r) {
                            int sl = wr * 128 + fi * 16 + quad * 4 + r;
                            Tb[el * LDT2 + sl] = (__bf16)(acc[fi][jj][r] + bb);
                        }
                    }
                }
            }
            __syncthreads();
            const int ch = (t & 31) * 8;
            const int rbase = t >> 5;          // [0,16)
            #pragma unroll
            for (int p = 0; p < 8; ++p) {
                int e = rbase + p * 16;
                bfx8 val = *(const bfx8*)&Tb[e * LDT2 + ch];
                *(bfx8*)&vT[(size_t)(bofs + n0 + half * 128 + e) * 1024 + s0 + ch] = val;
            }
        }
    }
}

// ---------------- K2: p_u = exp(q@k^T + mask), 128x128 causal, LDS-free ----
// grid 1152 = 8 xcd * (4 batch-groups * 36 causal tiles); K=768 uniform.
// Fragments loaded directly global->VGPR (q16/k16 are L3-resident); no
// staging, no K-loop barriers.
__global__ __launch_bounds__(256, 3) void logits_kernel(
    const f16* __restrict__ q16, const f16* __restrict__ k16,
    const float* __restrict__ amask, __bf16* __restrict__ pu, float* __restrict__ psum)
{
    const int f = blockIdx.x;
    const int xcd = f & 7;
    const int j = f >> 3;
    const int b = xcd + 8 * (j / 36);
    const int tile = j % 36;
    int mt = 0, base = 0;
    while (base + mt + 1 <= tile) { base += mt + 1; ++mt; }
    const int nt = tile - base;                 // nt <= mt (causal)
    const int m0 = mt * 128, n0 = nt * 128;
    const size_t pb = (size_t)b << 20;
    const size_t qb = (size_t)b * 1024 * 768;

    __shared__ float rs[2][128];

    const int t = threadIdx.x, lane = t & 63, wave = t >> 6;
    const int wm = (wave & 1) * 64, wn = (wave >> 1) * 64;
    const int quad = lane >> 4, l16 = lane & 15;

    const f16* qA = q16 + qb + (size_t)(m0 + wm + l16) * 768 + quad * 8;
    const f16* kB = k16 + qb + (size_t)(n0 + wn + l16) * 768 + quad * 8;

    f32x4 acc[4][4] = {};
    for (int k0 = 0; k0 < 768; k0 += 32) {
        f16x8 af[4], bg[4];
        #pragma unroll
        for (int i = 0; i < 4; ++i)
            af[i] = *(const f16x8*)(qA + (size_t)i * 16 * 768 + k0);
        #pragma unroll
        for (int jj = 0; jj < 4; ++jj)
            bg[jj] = *(const f16x8*)(kB + (size_t)jj * 16 * 768 + k0);
        #pragma unroll
        for (int i = 0; i < 4; ++i)
            #pragma unroll
            for (int jj = 0; jj < 4; ++jj)
                acc[i][jj] = MFMA_F16(af[i], bg[jj], acc[i][jj]);
    }

    float rp[4][4] = {};
    #pragma unroll
    for (int jj = 0; jj < 4; ++jj) {
        int col = n0 + wn + jj * 16 + l16;
        float am = (1.0f - amask[b * 1024 + col]) * -10000.0f;
        #pragma unroll
        for (int i = 0; i < 4; ++i)
            #pragma unroll
            for (int r = 0; r < 4; ++r) {
                int row = m0 + wm + i * 16 + quad * 4 + r;
                float s = acc[i][jj][r] + am;
                float pval = (col <= row) ? __expf(fminf(s, 80.0f)) : 0.0f;
                pu[pb + (size_t)row * 1024 + col] = (__bf16)pval;
                rp[i][r] += pval;
            }
    }
    #pragma unroll
    for (int i = 0; i < 4; ++i)
        #pragma unroll
        for (int r = 0; r < 4; ++r) {
            float v = rp[i][r];
            v += __shfl_xor(v, 1, 64);
            v += __shfl_xor(v, 2, 64);
            v += __shfl_xor(v, 4, 64);
            v += __shfl_xor(v, 8, 64);   // sum over l16 group
            if (l16 == 0) rs[wn >> 6][wm + i * 16 + quad * 4 + r] = v;
        }
    __syncthreads();
    if (t < 128)
        psum[((size_t)b * 1024 + m0 + t) * 8 + nt] = rs[0][t] + rs[1][t];
}

// ---------------- K3: h = (p_u @ v) / rowsum, 128x128, LDS-free -------------
// grid 1536 = 8 xcd * (4 batch-groups * 48 tiles), longest K (mt=7) first.
// pu/vT are L2-resident on the SAME XCD (b<->xcd affinity of producer and
// consumer) -> direct global->VGPR fragment loads, no staging/barriers.
__global__ __launch_bounds__(256, 4) void pv_kernel(
    const __bf16* __restrict__ pu, const __bf16* __restrict__ vT,
    const float* __restrict__ psum, __bf16* __restrict__ h)
{
    const int f = blockIdx.x;
    const int xcd = f & 7;
    const int j = f >> 3;
    const int b = xcd + 8 * (j / 48);
    const int tile = j % 48;
    const int mt = 7 - tile / 6, nt = tile % 6;
    const int m0 = mt * 128, n0 = nt * 128;
    const size_t pb = (size_t)b << 20;
    const size_t vb = (size_t)b * 768 * 1024;

    __shared__ float invl[128];

    const int t = threadIdx.x, lane = t & 63, wave = t >> 6;
    const int wm = (wave & 1) * 64, wn = (wave >> 1) * 64;
    const int quad = lane >> 4, l16 = lane & 15;

    if (t < 128) {
        int row = m0 + t;
        int lim = row >> 7;  // psum[row][n] written only for n <= row>>7
        const float* pr = &psum[((size_t)b * 1024 + row) * 8];
        float s = 0.f;
        #pragma unroll
        for (int n = 0; n < 8; ++n) s += (n <= lim) ? pr[n] : 0.f;
        invl[t] = 1.0f / s;
    }
    __syncthreads();   // single barrier; K-loop below is barrier-free

    const __bf16* pA = pu + pb + (size_t)(m0 + wm + l16) * 1024 + quad * 8;
    const __bf16* vB = vT + vb + (size_t)(n0 + wn + l16) * 1024 + quad * 8;

    const int kend = m0 + 128;  // p_u is exactly 0 above the diagonal
    f32x4 acc[4][4] = {};
    for (int k0 = 0; k0 < kend; k0 += 32) {
        bfx8 af[4], bg[4];
        #pragma unroll
        for (int i = 0; i < 4; ++i)
            af[i] = *(const bfx8*)(pA + (size_t)i * 16 * 1024 + k0);
        #pragma unroll
        for (int jj = 0; jj < 4; ++jj)
            bg[jj] = *(const bfx8*)(vB + (size_t)jj * 16 * 1024 + k0);
        #pragma unroll
        for (int i = 0; i < 4; ++i)
            #pragma unroll
            for (int jj = 0; jj < 4; ++jj)
                acc[i][jj] = MFMA_BF16(af[i], bg[jj], acc[i][jj]);
    }

    #pragma unroll
    for (int jj = 0; jj < 4; ++jj) {
        int col = n0 + wn + jj * 16 + l16;
        #pragma unroll
        for (int i = 0; i < 4; ++i)
            #pragma unroll
            for (int r = 0; r < 4; ++r) {
                int rl = wm + i * 16 + quad * 4 + r;
                h[((size_t)b * 1024 + m0 + rl) * 768 + col] = (__bf16)(acc[i][jj][r] * invl[rl]);
            }
    }
}

// ---------------- K4: out = relu(h @ W1b^T + b1) @ W2^T + b2 ----------------
__global__ __launch_bounds__(256) void mlp_kernel(
    const __bf16* __restrict__ h, const __bf16* __restrict__ W1b, const float* __restrict__ b1,
    const float* __restrict__ W2, const float* __restrict__ b2, float* __restrict__ out)
{
    const int wave = threadIdx.x >> 6, lane = threadIdx.x & 63;
    const int quad = lane >> 4, l16 = lane & 15;
    const int m0 = blockIdx.x * 64 + wave * 16;

    f32x4 acc[4] = {};
    for (int k0 = 0; k0 < 768; k0 += 32) {
        bfx8 af = *(const bfx8*)&h[(size_t)(m0 + l16) * 768 + k0 + quad * 8];
        #pragma unroll
        for (int jj = 0; jj < 4; ++jj) {
            bfx8 bg = *(const bfx8*)&W1b[(size_t)(jj * 16 + l16) * 768 + k0 + quad * 8];
            acc[jj] = MFMA_BF16(af, bg, acc[jj]);
        }
    }
    float part[4][2] = {};
    #pragma unroll
    for (int jj = 0; jj < 4; ++jj) {
        int c = jj * 16 + l16;
        float bb = b1[c];
        float w20 = W2[c], w21 = W2[64 + c];
        #pragma unroll
        for (int r = 0; r < 4; ++r) {
            float x = fmaxf(acc[jj][r] + bb, 0.f);
            part[r][0] += x * w20;
            part[r][1] += x * w21;
        }
    }
    #pragma unroll
    for (int off = 1; off < 16; off <<= 1)
        #pragma unroll
        for (int r = 0; r < 4; ++r) {
            part[r][0] += __shfl_xor(part[r][0], off, 64);
            part[r][1] += __shfl_xor(part[r][1], off, 64);
        }
    if (l16 == 0) {
        #pragma unroll
        for (int r = 0; r < 4; ++r) {
            int row = m0 + quad * 4 + r;
            out[(size_t)row * 2 + 0] = part[r][0] + b2[0];
            out[(size_t)row * 2 + 1] = part[r][1] + b2[1];
        }
    }
}

// ---------------------------------------------------------------------------
extern "C" void kernel_launch(void* const* d_in, const int* in_sizes, int n_in,
                              void* d_out, int out_size, void* d_ws, size_t ws_size,
                              hipStream_t stream)
{
    const float* hidden = (const float*)d_in[0];
    const float* amask  = (const float*)d_in[1];
    const float* Wk = (const float*)d_in[2];
    const float* bk = (const float*)d_in[3];
    const float* Wq = (const float*)d_in[4];
    const float* bq = (const float*)d_in[5];
    const float* Wv = (const float*)d_in[6];
    const float* bv = (const float*)d_in[7];
    const float* W1 = (const float*)d_in[8];
    const float* b1 = (const float*)d_in[9];
    const float* W2 = (const float*)d_in[10];
    const float* b2 = (const float*)d_in[11];
    float* out = (float*)d_out;

    char* ws = (char*)d_ws;
    const size_t MB = 1024 * 1024;
    f16* h16 = (f16*)ws;
    f16* wq16 = (f16*)(ws + 48 * MB);
    f16* wk16 = wq16 + 589824;
    f16* wv16 = wk16 + 589824;
    __bf16* pu  = (__bf16*)ws;                 // aliases h16/W16 (dead after qkv)
    float*  psum = (float*)(ws + 64 * MB);     // 32*1024*8 fp32 = 1 MB
    __bf16* w1b = (__bf16*)(ws + 65 * MB);     // 64*768 bf16 = 96 KB
    f16* q16 = (f16*)(ws + 66 * MB);
    f16* k16 = (f16*)(ws + 114 * MB);
    __bf16* vT = (__bf16*)(ws + 162 * MB);
    __bf16* h  = (__bf16*)(ws + 66 * MB);      // aliases q16 (dead after logits)
    const size_t NEED = 210 * MB;
    if (ws_size < NEED) {
        fprintf(stderr, "[Attn kernel] ws too small: %zu < %zu — skipping launches\n",
                ws_size, NEED);
        return;
    }

    cvt_all<<<2048, 256, 0, stream>>>(
        hidden, Wq, Wk, Wv, W1, h16, wq16, wk16, wv16, w1b);

    qkv_kernel<<<1152, 512, 0, stream>>>(
        h16, wq16, wk16, wv16, bq, bk, bv, q16, k16, vT);
    logits_kernel<<<1152, 256, 0, stream>>>(q16, k16, amask, pu, psum);
    pv_kernel<<<1536, 256, 0, stream>>>(pu, vT, psum, h);
    mlp_kernel<<<512, 256, 0, stream>>>(h, w1b, b1, W2, b2, out);
}

// Round 8
// 487.683 us; speedup vs baseline: 1.2076x; 1.2076x over previous
//
#include <hip/hip_runtime.h>
#include <hip/hip_bf16.h>
#include <cstdio>

// ---------------------------------------------------------------------------
// Attn_59940563583594: hidden[32,1024,768] -> QKV -> causal attn (no 1/sqrt(d))
//                      -> relu MLP(768->64) -> out[32,1024,2] fp32
// Numerics (verified R2-R8: absmax 9.8e-4 vs 3.8e-3 threshold):
//   f16 storage/MFMA for hidden/W/q/k, no-max softmax (exp clamp 80,
//   unnormalized bf16 p, fp32 row sums, normalize in PV), bf16 PV + MLP.
// R16 post-mortem: LDS-free direct-load logits/pv regressed (+96 us) ->
//   staging reverted to R15 forms.
// R17: vectorize ALL fragment epilogues via dead-LDS round-trip (the
//   pattern qkv's vT path already uses): qkv z<2 q/k stores (128 scalar
//   2B stores/thread -> 16x f16x8), logits pu stores (64 -> 8x bfx8),
//   pv h stores (64 -> 8x bfx8). Store-instr count /8, fully coalesced.
//   cvt kept at R16 grid-stride 16B form. qkv K-loop = R13 8-phase best;
//   logits/pv K-loops = R10/R15 128^2 2-phase staged.
// ---------------------------------------------------------------------------

typedef _Float16 f16;
typedef f16    f16x8 __attribute__((ext_vector_type(8)));
typedef f16    f16x4 __attribute__((ext_vector_type(4)));
typedef __bf16 bfx8  __attribute__((ext_vector_type(8)));
typedef __bf16 bfx4  __attribute__((ext_vector_type(4)));
typedef float  f32x4 __attribute__((ext_vector_type(4)));

#define MFMA_F16(a,b,c)  __builtin_amdgcn_mfma_f32_16x16x32_f16((a),(b),(c),0,0,0)
#define MFMA_BF16(a,b,c) __builtin_amdgcn_mfma_f32_16x16x32_bf16((a),(b),(c),0,0,0)

static constexpr int LDT2 = 264;  // qkv v-transpose / q-k store stride (16B-aligned)
static constexpr int LDP  = 136;  // logits/pv epilogue stride (16B-aligned)

__device__ __forceinline__ void gl_lds16(const void* g, void* l) {
    __builtin_amdgcn_global_load_lds(
        (const __attribute__((address_space(1))) void*)g,
        (__attribute__((address_space(3))) void*)l, 16, 0, 0);
}

// clobber-free waits, pinned with sched_barrier(0) (rule #18 / m201 pattern)
#define WAIT_VMCNT(n)                                        \
    do { asm volatile("s_waitcnt vmcnt(" #n ")");            \
         __builtin_amdgcn_sched_barrier(0); } while (0)
#define WAIT_LGKM0()                                         \
    do { asm volatile("s_waitcnt lgkmcnt(0)");               \
         __builtin_amdgcn_sched_barrier(0); } while (0)

// ---------------- fp32 -> f16/bf16 convert, grid-stride (R16) ---------------
__global__ __launch_bounds__(256) void cvt_all(
    const float* __restrict__ hidden,
    const float* __restrict__ Wq, const float* __restrict__ Wk, const float* __restrict__ Wv,
    const float* __restrict__ W1,
    f16* __restrict__ h16, f16* __restrict__ oq, f16* __restrict__ ok, f16* __restrict__ ov,
    __bf16* __restrict__ w1b)
{
    const int HID_C = 25165824 / 8;            // hidden chunks of 8 f32
    const int W_C   = 589824 / 8;              // per-weight chunks
    const int W1_C  = 49152 / 8;
    const int TOT   = HID_C + 3 * W_C + W1_C;
    for (int c = blockIdx.x * 256 + threadIdx.x; c < TOT; c += 2048 * 256) {
        const float* src;
        f16* dst = nullptr;
        __bf16* dstb = nullptr;
        int off;
        if (c < HID_C)                { src = hidden; dst = h16; off = c * 8; }
        else if (c < HID_C + W_C)     { src = Wq; dst = oq; off = (c - HID_C) * 8; }
        else if (c < HID_C + 2 * W_C) { src = Wk; dst = ok; off = (c - HID_C - W_C) * 8; }
        else if (c < HID_C + 3 * W_C) { src = Wv; dst = ov; off = (c - HID_C - 2 * W_C) * 8; }
        else                          { src = W1; dstb = w1b; off = (c - HID_C - 3 * W_C) * 8; }
        f32x4 a = *(const f32x4*)(src + off);
        f32x4 b = *(const f32x4*)(src + off + 4);
        if (dstb) {
            bfx8 o;
            #pragma unroll
            for (int e = 0; e < 4; ++e) { o[e] = (__bf16)a[e]; o[e + 4] = (__bf16)b[e]; }
            *(bfx8*)(dstb + off) = o;
        } else {
            f16x8 o;
            #pragma unroll
            for (int e = 0; e < 4; ++e) { o[e] = (f16)a[e]; o[e + 4] = (f16)b[e]; }
            *(f16x8*)(dst + off) = o;
        }
    }
}

// ---- 8-phase QPHASE (qkv only): {ds_read A | stage | gate | barrier | lgkm0
//                                  | 16 MFMA | barrier}
#define QPHASE(fr0, STAGE_STMT, GATE_STMT)                                        \
    {                                                                             \
        f16x8 afr[2][2];                                                          \
        _Pragma("unroll")                                                         \
        for (int i = 0; i < 2; ++i) {                                             \
            _Pragma("unroll")                                                     \
            for (int kk = 0; kk < 2; ++kk)                                        \
                afr[i][kk] = *(const f16x8*)&S[(kt & 1) * 32768 + kk * 8192 + (wr8 + (fr0) + i) * 512 + lq]; \
        }                                                                         \
        STAGE_STMT;                                                               \
        GATE_STMT;                                                                \
        __builtin_amdgcn_s_barrier();                                             \
        WAIT_LGKM0();                                                             \
        __builtin_amdgcn_s_setprio(1);                                            \
        _Pragma("unroll")                                                         \
        for (int i = 0; i < 2; ++i) {                                             \
            _Pragma("unroll")                                                     \
            for (int jj = 0; jj < 4; ++jj) {                                      \
                acc[(fr0) + i][jj] = MFMA_F16(afr[i][0], bfr[jj][0], acc[(fr0) + i][jj]); \
                acc[(fr0) + i][jj] = MFMA_F16(afr[i][1], bfr[jj][1], acc[(fr0) + i][jj]); \
            }                                                                     \
        }                                                                         \
        __builtin_amdgcn_s_setprio(0);                                            \
        __builtin_amdgcn_s_barrier();                                             \
    }

// ---------------- K1: fused q,k,v projections, 256x256 8-phase (R13) --------
// grid 1152 = 8 xcd * (3 nt * 3 z * 16 mi); mt = xcd + 8*mi; 512 threads.
__global__ __launch_bounds__(512, 2) void qkv_kernel(
    const f16* __restrict__ h16,
    const f16* __restrict__ wq, const f16* __restrict__ wk, const f16* __restrict__ wv,
    const float* __restrict__ bq, const float* __restrict__ bk, const float* __restrict__ bv,
    f16* __restrict__ q16, f16* __restrict__ k16, __bf16* __restrict__ vT)
{
    const int f = blockIdx.x;
    const int xcd = f & 7;
    const int j = f >> 3;
    const int nt = j % 3;
    const int z  = (j / 3) % 3;
    const int mi = j / 9;                 // [0,16)
    const int mt = xcd + 8 * mi;          // [0,128)
    const int m0 = mt * 256, n0 = nt * 256;

    const f16* W = (z == 0) ? wq : (z == 1) ? wk : wv;
    const float* bias = (z == 0) ? bq : (z == 1) ? bk : bv;

    __shared__ alignas(16) f16 S[67584];  // 132 KB (dbuf 128KB; epilogue 256x264)

    const int t = threadIdx.x, lane = t & 63, wave = t >> 6;
    const int wr = wave >> 2, wc = wave & 3;      // 2M x 4N wave grid
    const int wr8 = wr * 8;
    const int quad = lane >> 4, l16 = lane & 15;
    const int lq = quad * 128 + l16 * 8;

    const f16* gA = h16 + (size_t)(m0 + l16) * 768 + quad * 8;
    const f16* gB = W   + (size_t)(n0 + l16) * 768 + quad * 8;
    int gofs[2], lofs[2];
    #pragma unroll
    for (int u = 0; u < 2; ++u) {
        int unit = wave * 2 + u;
        int kk = unit >> 3, c = unit & 7;
        gofs[u] = c * 16 * 768 + kk * 32;
        lofs[u] = kk * 8192 + c * 512;
    }
    auto stage = [&](int kt, int mat, int half) {
        const f16* gp = (mat ? gB : gA) + half * (128 * 768) + kt * 64;
        f16* lp = &S[(kt & 1) * 32768 + mat * 16384 + half * 4096];
        gl_lds16(gp + gofs[0], lp + lofs[0]);
        gl_lds16(gp + gofs[1], lp + lofs[1]);
    };

    f32x4 acc[8][4] = {};

    stage(0, 0, 0); stage(0, 0, 1); stage(0, 1, 0); stage(0, 1, 1);
    stage(1, 1, 0); stage(1, 1, 1);
    WAIT_VMCNT(4);   // kt0 landed
    __builtin_amdgcn_s_barrier();

    f16x8 bfr[4][2];
    for (int kt = 0; kt < 12; ++kt) {
        #pragma unroll
        for (int jj = 0; jj < 4; ++jj) {
            #pragma unroll
            for (int kk = 0; kk < 2; ++kk)
                bfr[jj][kk] = *(const f16x8*)&S[(kt & 1) * 32768 + 16384 + kk * 8192 + (wc * 4 + jj) * 512 + lq];
        }
        QPHASE(0, { if (kt + 1 < 12) stage(kt + 1, 0, 0); }, {});
        QPHASE(2, { if (kt + 1 < 12) stage(kt + 1, 0, 1); }, {});
        QPHASE(4, { if (kt + 2 < 12) stage(kt + 2, 1, 0); }, {});
        QPHASE(6, { if (kt + 2 < 12) stage(kt + 2, 1, 1); },
               {
                   if (kt + 2 < 12)       WAIT_VMCNT(4);
                   else if (kt + 1 < 12)  WAIT_VMCNT(0);
               });
    }

    if (z < 2) {
        // R17: vectorized epilogue via LDS (256x264 f16), 16B coalesced stores
        f16* out = z ? k16 : q16;
        __syncthreads();
        #pragma unroll
        for (int jj = 0; jj < 4; ++jj) {
            int cl = wc * 64 + jj * 16 + l16;
            float bb = bias[n0 + cl];
            #pragma unroll
            for (int fi = 0; fi < 8; ++fi)
                #pragma unroll
                for (int r = 0; r < 4; ++r)
                    S[(wr * 128 + fi * 16 + quad * 4 + r) * LDT2 + cl] =
                        (f16)(acc[fi][jj][r] + bb);
        }
        __syncthreads();
        const int ch = (t & 31) * 8;
        const int rb = t >> 5;                 // [0,16)
        #pragma unroll
        for (int p = 0; p < 16; ++p) {
            int row = rb + p * 16;
            f16x8 val = *(const f16x8*)&S[row * LDT2 + ch];
            *(f16x8*)&out[(size_t)(m0 + row) * 768 + n0 + ch] = val;
        }
    } else {
        __bf16* Tb = (__bf16*)S;
        const int halfw = wc >> 1;
        const int bofs = (m0 >> 10) * 768;
        const int s0 = m0 & 1023;
        #pragma unroll
        for (int half = 0; half < 2; ++half) {
            __syncthreads();
            if (halfw == half) {
                #pragma unroll
                for (int jj = 0; jj < 4; ++jj) {
                    int el = (wc & 1) * 64 + jj * 16 + l16;
                    float bb = bias[n0 + half * 128 + el];
                    #pragma unroll
                    for (int fi = 0; fi < 8; ++fi) {
                        #pragma unroll
                        for (int r = 0; r < 4; ++r) {
                            int sl = wr * 128 + fi * 16 + quad * 4 + r;
                            Tb[el * LDT2 + sl] = (__bf16)(acc[fi][jj][r] + bb);
                        }
                    }
                }
            }
            __syncthreads();
            const int ch = (t & 31) * 8;
            const int rbase = t >> 5;          // [0,16)
            #pragma unroll
            for (int p = 0; p < 8; ++p) {
                int e = rbase + p * 16;
                bfx8 val = *(const bfx8*)&Tb[e * LDT2 + ch];
                *(bfx8*)&vT[(size_t)(bofs + n0 + half * 128 + e) * 1024 + s0 + ch] = val;
            }
        }
    }
}

// ---------------- K2: p_u = exp(q@k^T + mask), 128x128 causal tiles ---------
// grid 1152 = 8 xcd * (4 batch-groups * 36 causal tiles); K=768 uniform.
// R17: pu stores vectorized via LDS (128x136 bf16) -> 8x bfx8 per thread.
__global__ __launch_bounds__(256, 4) void logits_kernel(
    const f16* __restrict__ q16, const f16* __restrict__ k16,
    const float* __restrict__ amask, __bf16* __restrict__ pu, float* __restrict__ psum)
{
    const int f = blockIdx.x;
    const int xcd = f & 7;
    const int j = f >> 3;
    const int b = xcd + 8 * (j / 36);
    const int tile = j % 36;
    int mt = 0, base = 0;
    while (base + mt + 1 <= tile) { base += mt + 1; ++mt; }
    const int nt = tile - base;                 // nt <= mt (causal)
    const int m0 = mt * 128, n0 = nt * 128;
    const size_t pb = (size_t)b << 20;
    const size_t qb = (size_t)b * 1024 * 768;

    __shared__ alignas(16) char smem[34816];    // dbuf 32KB | epilogue 128x136 bf16
    f16 (*S)[8192] = (f16 (*)[8192])smem;
    __bf16* Pb = (__bf16*)smem;
    __shared__ float rs[2][128];

    const int t = threadIdx.x, lane = t & 63, wave = t >> 6;
    const int wm = (wave & 1) * 64, wn = (wave >> 1) * 64;
    const int quad = lane >> 4, l16 = lane & 15;

    const f16* gsrc[4];
    int ldst[4];
    #pragma unroll
    for (int u = 0; u < 4; ++u) {
        int c = wave * 4 + u;
        ldst[u] = c * 512;
        const f16* base2 = (c < 8) ? (q16 + qb + (size_t)(m0 + c * 16 + l16) * 768)
                                   : (k16 + qb + (size_t)(n0 + (c - 8) * 16 + l16) * 768);
        gsrc[u] = base2 + quad * 8;
    }

    f32x4 acc[4][4] = {};
    auto stage = [&](int k0, int buf) {
        #pragma unroll
        for (int u = 0; u < 4; ++u)
            gl_lds16(gsrc[u] + k0, &S[buf][ldst[u]]);
    };
    auto compute = [&](int buf) {
        f16x8 af[4], bg[4];
        #pragma unroll
        for (int i = 0; i < 4; ++i) {
            af[i] = *(const f16x8*)&S[buf][(wm / 16 + i) * 512 + quad * 128 + l16 * 8];
            bg[i] = *(const f16x8*)&S[buf][(8 + wn / 16 + i) * 512 + quad * 128 + l16 * 8];
        }
        #pragma unroll
        for (int i = 0; i < 4; ++i)
            #pragma unroll
            for (int jj = 0; jj < 4; ++jj)
                acc[i][jj] = MFMA_F16(af[i], bg[jj], acc[i][jj]);
    };

    stage(0, 0);
    int cur = 0;
    for (int k0 = 32; k0 < 768; k0 += 32) {
        __syncthreads();
        stage(k0, cur ^ 1);
        compute(cur);
        cur ^= 1;
    }
    __syncthreads();
    compute(cur);
    __syncthreads();   // S dbuf dead -> reuse as Pb

    float rp[4][4] = {};
    #pragma unroll
    for (int jj = 0; jj < 4; ++jj) {
        int cl = wn + jj * 16 + l16;
        int col = n0 + cl;
        float am = (1.0f - amask[b * 1024 + col]) * -10000.0f;
        #pragma unroll
        for (int i = 0; i < 4; ++i)
            #pragma unroll
            for (int r = 0; r < 4; ++r) {
                int rl = wm + i * 16 + quad * 4 + r;
                float s = acc[i][jj][r] + am;
                float pval = (col <= m0 + rl) ? __expf(fminf(s, 80.0f)) : 0.0f;
                Pb[rl * LDP + cl] = (__bf16)pval;
                rp[i][r] += pval;
            }
    }
    #pragma unroll
    for (int i = 0; i < 4; ++i)
        #pragma unroll
        for (int r = 0; r < 4; ++r) {
            float v = rp[i][r];
            v += __shfl_xor(v, 1, 64);
            v += __shfl_xor(v, 2, 64);
            v += __shfl_xor(v, 4, 64);
            v += __shfl_xor(v, 8, 64);   // sum over l16 group
            if (l16 == 0) rs[wn >> 6][wm + i * 16 + quad * 4 + r] = v;
        }
    __syncthreads();
    {
        const int ch = (t & 15) * 8;
        const int rb = t >> 4;               // [0,16)
        #pragma unroll
        for (int p = 0; p < 8; ++p) {
            int row = rb + p * 16;
            bfx8 val = *(const bfx8*)&Pb[row * LDP + ch];
            *(bfx8*)&pu[pb + (size_t)(m0 + row) * 1024 + n0 + ch] = val;
        }
    }
    if (t < 128)
        psum[((size_t)b * 1024 + m0 + t) * 8 + nt] = rs[0][t] + rs[1][t];
}

// ---------------- K3: h = (p_u @ v) / rowsum, 128x128 tiles -----------------
// grid 1536 = 8 xcd * (4 batch-groups * 48 tiles), longest K (mt=7) first.
// R17: h stores vectorized via LDS (128x136 bf16) -> 8x bfx8 per thread.
__global__ __launch_bounds__(256, 4) void pv_kernel(
    const __bf16* __restrict__ pu, const __bf16* __restrict__ vT,
    const float* __restrict__ psum, __bf16* __restrict__ h)
{
    const int f = blockIdx.x;
    const int xcd = f & 7;
    const int j = f >> 3;
    const int b = xcd + 8 * (j / 48);
    const int tile = j % 48;
    const int mt = 7 - tile / 6, nt = tile % 6;
    const int m0 = mt * 128, n0 = nt * 128;
    const size_t pb = (size_t)b << 20;
    const size_t vb = (size_t)b * 768 * 1024;

    __shared__ alignas(16) char smem[34816];    // dbuf 32KB | epilogue 128x136 bf16
    __bf16 (*S)[8192] = (__bf16 (*)[8192])smem;
    __bf16* Hb = (__bf16*)smem;
    __shared__ float invl[128];

    const int t = threadIdx.x, lane = t & 63, wave = t >> 6;
    const int wm = (wave & 1) * 64, wn = (wave >> 1) * 64;
    const int quad = lane >> 4, l16 = lane & 15;

    if (t < 128) {
        int row = m0 + t;
        int lim = row >> 7;  // psum[row][n] written only for n <= row>>7
        const float* pr = &psum[((size_t)b * 1024 + row) * 8];
        float s = 0.f;
        #pragma unroll
        for (int n = 0; n < 8; ++n) s += (n <= lim) ? pr[n] : 0.f;
        invl[t] = 1.0f / s;
    }

    const __bf16* gsrc[4];
    int ldst[4];
    #pragma unroll
    for (int u = 0; u < 4; ++u) {
        int c = wave * 4 + u;
        ldst[u] = c * 512;
        const __bf16* base = (c < 8) ? (pu + pb + (size_t)(m0 + c * 16 + l16) * 1024)
                                     : (vT + vb + (size_t)(n0 + (c - 8) * 16 + l16) * 1024);
        gsrc[u] = base + quad * 8;
    }

    f32x4 acc[4][4] = {};
    auto stage = [&](int k0, int buf) {
        #pragma unroll
        for (int u = 0; u < 4; ++u)
            gl_lds16(gsrc[u] + k0, &S[buf][ldst[u]]);
    };
    auto compute = [&](int buf) {
        bfx8 af[4], bg[4];
        #pragma unroll
        for (int i = 0; i < 4; ++i) {
            af[i] = *(const bfx8*)&S[buf][(wm / 16 + i) * 512 + quad * 128 + l16 * 8];
            bg[i] = *(const bfx8*)&S[buf][(8 + wn / 16 + i) * 512 + quad * 128 + l16 * 8];
        }
        #pragma unroll
        for (int i = 0; i < 4; ++i)
            #pragma unroll
            for (int jj = 0; jj < 4; ++jj)
                acc[i][jj] = MFMA_BF16(af[i], bg[jj], acc[i][jj]);
    };

    const int kend = m0 + 128;  // p_u is exactly 0 above the diagonal
    stage(0, 0);
    int cur = 0;
    for (int k0 = 32; k0 < kend; k0 += 32) {
        __syncthreads();
        stage(k0, cur ^ 1);
        compute(cur);
        cur ^= 1;
    }
    __syncthreads();
    compute(cur);
    __syncthreads();   // S dbuf dead -> reuse as Hb

    #pragma unroll
    for (int jj = 0; jj < 4; ++jj) {
        int cl = wn + jj * 16 + l16;
        #pragma unroll
        for (int i = 0; i < 4; ++i)
            #pragma unroll
            for (int r = 0; r < 4; ++r) {
                int rl = wm + i * 16 + quad * 4 + r;
                Hb[rl * LDP + cl] = (__bf16)(acc[i][jj][r] * invl[rl]);
            }
    }
    __syncthreads();
    {
        const int ch = (t & 15) * 8;
        const int rb = t >> 4;               // [0,16)
        #pragma unroll
        for (int p = 0; p < 8; ++p) {
            int row = rb + p * 16;
            bfx8 val = *(const bfx8*)&Hb[row * LDP + ch];
            *(bfx8*)&h[((size_t)b * 1024 + m0 + row) * 768 + n0 + ch] = val;
        }
    }
}

// ---------------- K4: out = relu(h @ W1b^T + b1) @ W2^T + b2 ----------------
__global__ __launch_bounds__(256) void mlp_kernel(
    const __bf16* __restrict__ h, const __bf16* __restrict__ W1b, const float* __restrict__ b1,
    const float* __restrict__ W2, const float* __restrict__ b2, float* __restrict__ out)
{
    const int wave = threadIdx.x >> 6, lane = threadIdx.x & 63;
    const int quad = lane >> 4, l16 = lane & 15;
    const int m0 = blockIdx.x * 64 + wave * 16;

    f32x4 acc[4] = {};
    for (int k0 = 0; k0 < 768; k0 += 32) {
        bfx8 af = *(const bfx8*)&h[(size_t)(m0 + l16) * 768 + k0 + quad * 8];
        #pragma unroll
        for (int jj = 0; jj < 4; ++jj) {
            bfx8 bg = *(const bfx8*)&W1b[(size_t)(jj * 16 + l16) * 768 + k0 + quad * 8];
            acc[jj] = MFMA_BF16(af, bg, acc[jj]);
        }
    }
    float part[4][2] = {};
    #pragma unroll
    for (int jj = 0; jj < 4; ++jj) {
        int c = jj * 16 + l16;
        float bb = b1[c];
        float w20 = W2[c], w21 = W2[64 + c];
        #pragma unroll
        for (int r = 0; r < 4; ++r) {
            float x = fmaxf(acc[jj][r] + bb, 0.f);
            part[r][0] += x * w20;
            part[r][1] += x * w21;
        }
    }
    #pragma unroll
    for (int off = 1; off < 16; off <<= 1)
        #pragma unroll
        for (int r = 0; r < 4; ++r) {
            part[r][0] += __shfl_xor(part[r][0], off, 64);
            part[r][1] += __shfl_xor(part[r][1], off, 64);
        }
    if (l16 == 0) {
        #pragma unroll
        for (int r = 0; r < 4; ++r) {
            int row = m0 + quad * 4 + r;
            out[(size_t)row * 2 + 0] = part[r][0] + b2[0];
            out[(size_t)row * 2 + 1] = part[r][1] + b2[1];
        }
    }
}

// ---------------------------------------------------------------------------
extern "C" void kernel_launch(void* const* d_in, const int* in_sizes, int n_in,
                              void* d_out, int out_size, void* d_ws, size_t ws_size,
                              hipStream_t stream)
{
    const float* hidden = (const float*)d_in[0];
    const float* amask  = (const float*)d_in[1];
    const float* Wk = (const float*)d_in[2];
    const float* bk = (const float*)d_in[3];
    const float* Wq = (const float*)d_in[4];
    const float* bq = (const float*)d_in[5];
    const float* Wv = (const float*)d_in[6];
    const float* bv = (const float*)d_in[7];
    const float* W1 = (const float*)d_in[8];
    const float* b1 = (const float*)d_in[9];
    const float* W2 = (const float*)d_in[10];
    const float* b2 = (const float*)d_in[11];
    float* out = (float*)d_out;

    char* ws = (char*)d_ws;
    const size_t MB = 1024 * 1024;
    f16* h16 = (f16*)ws;
    f16* wq16 = (f16*)(ws + 48 * MB);
    f16* wk16 = wq16 + 589824;
    f16* wv16 = wk16 + 589824;
    __bf16* pu  = (__bf16*)ws;                 // aliases h16/W16 (dead after qkv)
    float*  psum = (float*)(ws + 64 * MB);     // 32*1024*8 fp32 = 1 MB
    __bf16* w1b = (__bf16*)(ws + 65 * MB);     // 64*768 bf16 = 96 KB
    f16* q16 = (f16*)(ws + 66 * MB);
    f16* k16 = (f16*)(ws + 114 * MB);
    __bf16* vT = (__bf16*)(ws + 162 * MB);
    __bf16* h  = (__bf16*)(ws + 66 * MB);      // aliases q16 (dead after logits)
    const size_t NEED = 210 * MB;
    if (ws_size < NEED) {
        fprintf(stderr, "[Attn kernel] ws too small: %zu < %zu — skipping launches\n",
                ws_size, NEED);
        return;
    }

    cvt_all<<<2048, 256, 0, stream>>>(
        hidden, Wq, Wk, Wv, W1, h16, wq16, wk16, wv16, w1b);

    qkv_kernel<<<1152, 512, 0, stream>>>(
        h16, wq16, wk16, wv16, bq, bk, bv, q16, k16, vT);
    logits_kernel<<<1152, 256, 0, stream>>>(q16, k16, amask, pu, psum);
    pv_kernel<<<1536, 256, 0, stream>>>(pu, vT, psum, h);
    mlp_kernel<<<512, 256, 0, stream>>>(h, w1b, b1, W2, b2, out);
}